// Round 3
// baseline (447.583 us; speedup 1.0000x reference)
//
#include <hip/hip_runtime.h>

#define B_  64
#define H_  32
#define D_  4096
#define KD  128
#define VD  128
#define M_  4095
#define M1_ 4096
#define NCHUNK 32
#define LOG2E 1.44269504088896f

// ---- workspace layout (float offsets) ----
#define WS_P      0ull
#define WS_Q      4456448ull
#define WS_STATS  4718592ull
#define WS_O      4849664ull
#define WS_OPART  5111808ull

// ---------------- K1a: partial projections (q, k_new, v_new) ----------------
// grid (16 d-chunks, 34 hx) ; hx<32 -> Wq[h], hx==32 -> Wk, hx==33 -> Wv
__global__ __launch_bounds__(256) void k_proj_partial(
    const float* __restrict__ x, const float* __restrict__ Wq,
    const float* __restrict__ Wk, const float* __restrict__ Wv,
    float* __restrict__ P) {
  __shared__ float xs[64][256];   // 64 KB
  const int dc = blockIdx.x;      // 0..15
  const int hx = blockIdx.y;      // 0..33
  const int t  = threadIdx.x;
  const float* xsrc = x + dc * 256;
  #pragma unroll
  for (int j = 0; j < 16; ++j) {
    int f = t + 256 * j;          // f4 index 0..4095
    int row = f >> 6, c4 = f & 63;
    *(float4*)&xs[row][c4 * 4] =
        *(const float4*)(xsrc + (size_t)row * D_ + c4 * 4);
  }
  __syncthreads();
  const int bq = t >> 4;          // 0..15 (4 b each)
  const int kg = t & 15;          // 0..15 (8 k each)
  const int b0 = bq * 4;
  const float* W = (hx < H_) ? (Wq + (size_t)hx * D_ * KD)
                             : ((hx == H_) ? Wk : Wv);
  const float* wp = W + (size_t)(dc * 256) * KD + kg * 8;
  float acc[4][8];
  #pragma unroll
  for (int i = 0; i < 4; ++i)
    #pragma unroll
    for (int j = 0; j < 8; ++j) acc[i][j] = 0.f;
  #pragma unroll 2
  for (int d = 0; d < 256; ++d) {
    float4 w0 = *(const float4*)(wp + (size_t)d * KD);
    float4 w1 = *(const float4*)(wp + (size_t)d * KD + 4);
    float xv[4];
    #pragma unroll
    for (int i = 0; i < 4; ++i) xv[i] = xs[b0 + i][d];
    #pragma unroll
    for (int i = 0; i < 4; ++i) {
      acc[i][0] += xv[i] * w0.x; acc[i][1] += xv[i] * w0.y;
      acc[i][2] += xv[i] * w0.z; acc[i][3] += xv[i] * w0.w;
      acc[i][4] += xv[i] * w1.x; acc[i][5] += xv[i] * w1.y;
      acc[i][6] += xv[i] * w1.z; acc[i][7] += xv[i] * w1.w;
    }
  }
  #pragma unroll
  for (int i = 0; i < 4; ++i) {
    size_t base = ((size_t)(dc * 64 + b0 + i) * 34 + hx) * KD + kg * 8;
    *(float4*)&P[base]     = make_float4(acc[i][0], acc[i][1], acc[i][2], acc[i][3]);
    *(float4*)&P[base + 4] = make_float4(acc[i][4], acc[i][5], acc[i][6], acc[i][7]);
  }
}

// ---------------- K1b: reduce partials -> q, Kc[.,M,:], Vc[.,M,:] ----------
__global__ __launch_bounds__(256) void k_proj_reduce(
    const float* __restrict__ P, float* __restrict__ q,
    float* __restrict__ Kc, float* __restrict__ Vc) {
  int i = blockIdx.x * 256 + threadIdx.x;  // < 64*34*128 = 278528
  int k = i & 127;
  int hx = (i >> 7) % 34;
  int b = i / (128 * 34);
  float s = 0.f;
  #pragma unroll
  for (int dc = 0; dc < 16; ++dc)
    s += P[(size_t)dc * (64 * 34 * 128) + (size_t)(b * 34 + hx) * 128 + k];
  if (hx < H_)       q[((size_t)b * H_ + hx) * KD + k] = s;
  else if (hx == H_) Kc[((size_t)b * M1_ + M_) * KD + k] = s;
  else               Vc[((size_t)b * M1_ + M_) * VD + k] = s;
}

// ---------------- K2: flash attention chunk kernel (reg-prefetch pipelined) -
// grid (32 m-chunks of 128, 64 b). Streams K then V through one LDS buffer;
// next half's global loads are issued into registers BEFORE computing the
// current half, so HBM latency hides under the dot-product / softmax VALU.
__global__ __launch_bounds__(256) void k_flash(
    const float* __restrict__ prevK, const float* __restrict__ prevV,
    const float* __restrict__ q, float* __restrict__ Kc, float* __restrict__ Vc,
    float* __restrict__ o_part, float* __restrict__ stats) {
  __shared__ float buf[64][132];   // 33.8 KB staging (K halves, then V halves)
  __shared__ float qs[32][132];    // 16.9 KB
  __shared__ float wl[128][36];    // 18.4 KB logits/weights [m][h]
  const int chunk = blockIdx.x;    // 0..31
  const int b = blockIdx.y;
  const int t = threadIdx.x;
  const int m0 = chunk * 128;

  const int r_st  = t >> 3;        // staging row for this thread? (unused helper)
  (void)r_st;

  // ---- issue q loads + K-half0 loads ----
  const float* qsrc = q + (size_t)b * H_ * KD;
  float4 qreg[4];
  #pragma unroll
  for (int j = 0; j < 4; ++j) {
    int f = t + 256 * j, row = f >> 5, c4 = f & 31;
    qreg[j] = *(const float4*)(qsrc + (size_t)row * KD + c4 * 4);
  }
  float4 kreg[8];
  #pragma unroll
  for (int j = 0; j < 8; ++j) {
    int f = t + 256 * j, r = f >> 5, c4 = f & 31;
    int m = m0 + r;                // half 0: never the appended row
    kreg[j] = *(const float4*)(prevK + ((size_t)b * M_ + m) * KD + c4 * 4);
  }
  // write q + K-half0 to LDS, store Kc-half0
  #pragma unroll
  for (int j = 0; j < 4; ++j) {
    int f = t + 256 * j, row = f >> 5, c4 = f & 31;
    *(float4*)&qs[row][c4 * 4] = qreg[j];
  }
  #pragma unroll
  for (int j = 0; j < 8; ++j) {
    int f = t + 256 * j, r = f >> 5, c4 = f & 31;
    int m = m0 + r;
    *(float4*)&buf[r][c4 * 4] = kreg[j];
    *(float4*)(Kc + ((size_t)b * M1_ + m) * KD + c4 * 4) = kreg[j];
  }
  __syncthreads();

  // ---- issue K-half1 loads (in flight during half0 compute) ----
  float4 kreg1[8];
  #pragma unroll
  for (int j = 0; j < 8; ++j) {
    int f = t + 256 * j, r = f >> 5, c4 = f & 31;
    int m = m0 + 64 + r;
    kreg1[j] = (m < M_)
        ? *(const float4*)(prevK + ((size_t)b * M_ + m) * KD + c4 * 4)
        : *(const float4*)(Kc + ((size_t)b * M1_ + M_) * KD + c4 * 4);
  }

  const int hg = t >> 4, mg = t & 15, h0 = hg * 2;
  // ---- logits half0 ----
  {
    float acc[2][4];
    #pragma unroll
    for (int hi = 0; hi < 2; ++hi)
      #pragma unroll
      for (int i = 0; i < 4; ++i) acc[hi][i] = 0.f;
    #pragma unroll 2
    for (int k4 = 0; k4 < 32; ++k4) {
      float4 qa = *(const float4*)&qs[h0][k4 * 4];
      float4 qb = *(const float4*)&qs[h0 + 1][k4 * 4];
      float4 kv[4];
      #pragma unroll
      for (int i = 0; i < 4; ++i) kv[i] = *(const float4*)&buf[mg + i * 16][k4 * 4];
      #pragma unroll
      for (int i = 0; i < 4; ++i) {
        acc[0][i] += qa.x * kv[i].x + qa.y * kv[i].y + qa.z * kv[i].z + qa.w * kv[i].w;
        acc[1][i] += qb.x * kv[i].x + qb.y * kv[i].y + qb.z * kv[i].z + qb.w * kv[i].w;
      }
    }
    #pragma unroll
    for (int hi = 0; hi < 2; ++hi)
      #pragma unroll
      for (int i = 0; i < 4; ++i)
        wl[mg + i * 16][h0 + hi] = acc[hi][i];
  }
  __syncthreads();                 // half0 compute done -> buf reusable

  // ---- write K-half1, store Kc-half1 ----
  #pragma unroll
  for (int j = 0; j < 8; ++j) {
    int f = t + 256 * j, r = f >> 5, c4 = f & 31;
    int m = m0 + 64 + r;
    *(float4*)&buf[r][c4 * 4] = kreg1[j];
    if (m < M_) *(float4*)(Kc + ((size_t)b * M1_ + m) * KD + c4 * 4) = kreg1[j];
  }
  __syncthreads();

  // ---- issue V-half0 loads (in flight during half1 compute + softmax) ----
  float4 vreg[8];
  #pragma unroll
  for (int j = 0; j < 8; ++j) {
    int f = t + 256 * j, r = f >> 5, c4 = f & 31;
    int m = m0 + r;                // half 0: never the appended row
    vreg[j] = *(const float4*)(prevV + ((size_t)b * M_ + m) * VD + c4 * 4);
  }

  // ---- logits half1 ----
  {
    float acc[2][4];
    #pragma unroll
    for (int hi = 0; hi < 2; ++hi)
      #pragma unroll
      for (int i = 0; i < 4; ++i) acc[hi][i] = 0.f;
    #pragma unroll 2
    for (int k4 = 0; k4 < 32; ++k4) {
      float4 qa = *(const float4*)&qs[h0][k4 * 4];
      float4 qb = *(const float4*)&qs[h0 + 1][k4 * 4];
      float4 kv[4];
      #pragma unroll
      for (int i = 0; i < 4; ++i) kv[i] = *(const float4*)&buf[mg + i * 16][k4 * 4];
      #pragma unroll
      for (int i = 0; i < 4; ++i) {
        acc[0][i] += qa.x * kv[i].x + qa.y * kv[i].y + qa.z * kv[i].z + qa.w * kv[i].w;
        acc[1][i] += qb.x * kv[i].x + qb.y * kv[i].y + qb.z * kv[i].z + qb.w * kv[i].w;
      }
    }
    #pragma unroll
    for (int hi = 0; hi < 2; ++hi)
      #pragma unroll
      for (int i = 0; i < 4; ++i)
        wl[64 + mg + i * 16][h0 + hi] = acc[hi][i];
  }
  __syncthreads();                 // wl fully written

  // ---- chunk-local softmax over wl columns (V-half0 loads in flight) ----
  {
    const int h = t >> 3, s8 = t & 7;   // 8 threads per h
    float vals[16];
    float mx = -3.402823466e38f;
    #pragma unroll
    for (int i = 0; i < 16; ++i) {      // m = i*8 + s8 (strided: avoids bank alias)
      vals[i] = wl[i * 8 + s8][h];
      mx = fmaxf(mx, vals[i]);
    }
    mx = fmaxf(mx, __shfl_xor(mx, 1));
    mx = fmaxf(mx, __shfl_xor(mx, 2));
    mx = fmaxf(mx, __shfl_xor(mx, 4));
    float sum = 0.f;
    #pragma unroll
    for (int i = 0; i < 16; ++i) {
      float e = exp2f((vals[i] - mx) * LOG2E);
      wl[i * 8 + s8][h] = e;
      sum += e;
    }
    sum += __shfl_xor(sum, 1);
    sum += __shfl_xor(sum, 2);
    sum += __shfl_xor(sum, 4);
    if (s8 == 0) {
      size_t sb = (((size_t)b * H_ + h) * NCHUNK + chunk) * 2;
      stats[sb]     = mx;
      stats[sb + 1] = sum;
    }
  }
  __syncthreads();                 // softmax done; buf last read 2 barriers ago

  // ---- write V-half0, store Vc-half0 ----
  #pragma unroll
  for (int j = 0; j < 8; ++j) {
    int f = t + 256 * j, r = f >> 5, c4 = f & 31;
    int m = m0 + r;
    *(float4*)&buf[r][c4 * 4] = vreg[j];
    *(float4*)(Vc + ((size_t)b * M1_ + m) * VD + c4 * 4) = vreg[j];
  }
  __syncthreads();

  // ---- issue V-half1 loads (in flight during PV half0) ----
  float4 vreg1[8];
  #pragma unroll
  for (int j = 0; j < 8; ++j) {
    int f = t + 256 * j, r = f >> 5, c4 = f & 31;
    int m = m0 + 64 + r;
    vreg1[j] = (m < M_)
        ? *(const float4*)(prevV + ((size_t)b * M_ + m) * VD + c4 * 4)
        : *(const float4*)(Vc + ((size_t)b * M1_ + M_) * VD + c4 * 4);
  }

  const int hg2 = t >> 5, vg = t & 31;
  const int h0v = hg2 * 4, v0 = vg * 4;
  float acc2[4][4];
  #pragma unroll
  for (int hi = 0; hi < 4; ++hi)
    #pragma unroll
    for (int vi = 0; vi < 4; ++vi) acc2[hi][vi] = 0.f;

  // ---- PV half0 ----
  #pragma unroll 4
  for (int mm = 0; mm < 64; ++mm) {
    float4 w4 = *(const float4*)&wl[mm][h0v];
    float4 v4 = *(const float4*)&buf[mm][v0];
    float wv[4] = {w4.x, w4.y, w4.z, w4.w};
    float vv[4] = {v4.x, v4.y, v4.z, v4.w};
    #pragma unroll
    for (int hi = 0; hi < 4; ++hi)
      #pragma unroll
      for (int vi = 0; vi < 4; ++vi) acc2[hi][vi] += wv[hi] * vv[vi];
  }
  __syncthreads();                 // PV half0 done -> buf reusable

  // ---- write V-half1, store Vc-half1 ----
  #pragma unroll
  for (int j = 0; j < 8; ++j) {
    int f = t + 256 * j, r = f >> 5, c4 = f & 31;
    int m = m0 + 64 + r;
    *(float4*)&buf[r][c4 * 4] = vreg1[j];
    if (m < M_) *(float4*)(Vc + ((size_t)b * M1_ + m) * VD + c4 * 4) = vreg1[j];
  }
  __syncthreads();

  // ---- PV half1 ----
  #pragma unroll 4
  for (int mm = 0; mm < 64; ++mm) {
    float4 w4 = *(const float4*)&wl[64 + mm][h0v];
    float4 v4 = *(const float4*)&buf[mm][v0];
    float wv[4] = {w4.x, w4.y, w4.z, w4.w};
    float vv[4] = {v4.x, v4.y, v4.z, v4.w};
    #pragma unroll
    for (int hi = 0; hi < 4; ++hi)
      #pragma unroll
      for (int vi = 0; vi < 4; ++vi) acc2[hi][vi] += wv[hi] * vv[vi];
  }

  #pragma unroll
  for (int hi = 0; hi < 4; ++hi) {
    size_t base = ((size_t)(chunk * B_ + b) * H_ + h0v + hi) * VD + v0;
    *(float4*)&o_part[base] =
        make_float4(acc2[hi][0], acc2[hi][1], acc2[hi][2], acc2[hi][3]);
  }
}

// ---------------- K3: flash combine -> o -----------------------------------
// grid 2048 = (b*H + h); 128 threads (one per v)
__global__ __launch_bounds__(128) void k_combine(
    const float* __restrict__ o_part, const float* __restrict__ stats,
    float* __restrict__ o) {
  const int bh = blockIdx.x;
  const int t = threadIdx.x;
  __shared__ float st[64];
  if (t < 64) st[t] = stats[(size_t)bh * 64 + t];
  __syncthreads();
  float M = -3.402823466e38f;
  #pragma unroll
  for (int c = 0; c < NCHUNK; ++c) M = fmaxf(M, st[2 * c]);
  float wc[NCHUNK];
  float denom = 0.f;
  #pragma unroll
  for (int c = 0; c < NCHUNK; ++c) {
    float e = exp2f((st[2 * c] - M) * LOG2E);
    wc[c] = e;
    denom += st[2 * c + 1] * e;
  }
  const float inv = 1.0f / denom;
  const int b = bh >> 5, h = bh & 31;
  float acc = 0.f;
  #pragma unroll 4
  for (int c = 0; c < NCHUNK; ++c)
    acc += wc[c] * o_part[((size_t)(c * B_ + b) * H_ + h) * VD + t];
  o[(size_t)bh * VD + t] = acc * inv;
}

// ---------------- K5: partial y = o . Wo -----------------------------------
// grid (32 d-chunks of 128, 16 hv-chunks of 256)
__global__ __launch_bounds__(256) void k_out_partial(
    const float* __restrict__ o, const float* __restrict__ Wo,
    float* __restrict__ Py) {
  __shared__ float os[64][256];   // 64 KB
  const int dc = blockIdx.x;      // 0..31
  const int hvc = blockIdx.y;     // 0..15
  const int t = threadIdx.x;
  #pragma unroll
  for (int j = 0; j < 16; ++j) {
    int f = t + 256 * j;          // 0..4095 f4 over [64][64]
    int row = f >> 6, c4 = f & 63;
    *(float4*)&os[row][c4 * 4] =
        *(const float4*)(o + (size_t)row * 4096 + hvc * 256 + c4 * 4);
  }
  __syncthreads();
  const int bq = t >> 4, dg = t & 15;
  const int b0 = bq * 4;
  const float* wp = Wo + (size_t)(hvc * 256) * D_ + dc * 128 + dg * 8;
  float acc[4][8];
  #pragma unroll
  for (int i = 0; i < 4; ++i)
    #pragma unroll
    for (int j = 0; j < 8; ++j) acc[i][j] = 0.f;
  #pragma unroll 2
  for (int hv = 0; hv < 256; ++hv) {
    float4 w0 = *(const float4*)(wp + (size_t)hv * D_);
    float4 w1 = *(const float4*)(wp + (size_t)hv * D_ + 4);
    float ov[4];
    #pragma unroll
    for (int i = 0; i < 4; ++i) ov[i] = os[b0 + i][hv];
    #pragma unroll
    for (int i = 0; i < 4; ++i) {
      acc[i][0] += ov[i] * w0.x; acc[i][1] += ov[i] * w0.y;
      acc[i][2] += ov[i] * w0.z; acc[i][3] += ov[i] * w0.w;
      acc[i][4] += ov[i] * w1.x; acc[i][5] += ov[i] * w1.y;
      acc[i][6] += ov[i] * w1.z; acc[i][7] += ov[i] * w1.w;
    }
  }
  #pragma unroll
  for (int i = 0; i < 4; ++i) {
    size_t base = ((size_t)hvc * 64 + b0 + i) * 4096 + dc * 128 + dg * 8;
    *(float4*)&Py[base]     = make_float4(acc[i][0], acc[i][1], acc[i][2], acc[i][3]);
    *(float4*)&Py[base + 4] = make_float4(acc[i][4], acc[i][5], acc[i][6], acc[i][7]);
  }
}

// ---------------- K5b: reduce partial y ------------------------------------
__global__ __launch_bounds__(256) void k_yreduce(
    const float* __restrict__ Py, float* __restrict__ y) {
  int i = blockIdx.x * 256 + threadIdx.x;  // < 262144
  float s = 0.f;
  #pragma unroll
  for (int c = 0; c < 16; ++c) s += Py[(size_t)c * 262144 + i];
  y[i] = s;
}

extern "C" void kernel_launch(void* const* d_in, const int* in_sizes, int n_in,
                              void* d_out, int out_size, void* d_ws, size_t ws_size,
                              hipStream_t stream) {
  const float* x     = (const float*)d_in[0];
  const float* prevK = (const float*)d_in[1];
  const float* prevV = (const float*)d_in[2];
  const float* Wq    = (const float*)d_in[3];
  const float* Wk    = (const float*)d_in[4];
  const float* Wv    = (const float*)d_in[5];
  const float* Wo    = (const float*)d_in[6];

  float* y  = (float*)d_out;                 // [64][4096]
  float* Kc = y + (size_t)B_ * D_;           // [64][4096][128]
  float* Vc = Kc + (size_t)B_ * M1_ * KD;    // [64][4096][128]

  float* ws     = (float*)d_ws;
  float* P      = ws + WS_P;       // proj partials, later Py
  float* q      = ws + WS_Q;
  float* stats  = ws + WS_STATS;
  float* o      = ws + WS_O;
  float* o_part = ws + WS_OPART;

  k_proj_partial<<<dim3(16, 34), 256, 0, stream>>>(x, Wq, Wk, Wv, P);
  k_proj_reduce<<<1088, 256, 0, stream>>>(P, q, Kc, Vc);
  k_flash<<<dim3(32, 64), 256, 0, stream>>>(prevK, prevV, q, Kc, Vc, o_part, stats);
  k_combine<<<2048, 128, 0, stream>>>(o_part, stats, o);
  k_out_partial<<<dim3(32, 16), 256, 0, stream>>>(o, Wo, P);
  k_yreduce<<<1024, 256, 0, stream>>>(P, y);
}

// Round 4
// 301.006 us; speedup vs baseline: 1.4870x; 1.4870x over previous
//
#include <hip/hip_runtime.h>

#define B_  64
#define H_  32
#define D_  4096
#define KD  128
#define VD  128
#define M_  4095
#define M1_ 4096
#define NCHUNK 32
#define LOG2E 1.44269504088896f

// ---- workspace layout (float offsets) ----
#define WS_P      0ull
#define WS_Q      4456448ull
#define WS_STATS  4718592ull
#define WS_O      4849664ull
#define WS_OPART  5111808ull

// ---------------- K1a: partial projections (q, k_new, v_new) ----------------
// grid (16 d-chunks, 34 hx) ; hx<32 -> Wq[h], hx==32 -> Wk, hx==33 -> Wv
__global__ __launch_bounds__(256) void k_proj_partial(
    const float* __restrict__ x, const float* __restrict__ Wq,
    const float* __restrict__ Wk, const float* __restrict__ Wv,
    float* __restrict__ P) {
  __shared__ float xs[64][256];   // 64 KB -> 2 blocks/CU
  const int dc = blockIdx.x;      // 0..15
  const int hx = blockIdx.y;      // 0..33
  const int t  = threadIdx.x;
  const float* xsrc = x + dc * 256;
  #pragma unroll
  for (int j = 0; j < 16; ++j) {
    int f = t + 256 * j;          // f4 index 0..4095
    int row = f >> 6, c4 = f & 63;
    *(float4*)&xs[row][c4 * 4] =
        *(const float4*)(xsrc + (size_t)row * D_ + c4 * 4);
  }
  __syncthreads();
  const int bq = t >> 4;          // 0..15 (4 b each)
  const int kg = t & 15;          // 0..15 (8 k each)
  const int b0 = bq * 4;
  const float* W = (hx < H_) ? (Wq + (size_t)hx * D_ * KD)
                             : ((hx == H_) ? Wk : Wv);
  const float* wp = W + (size_t)(dc * 256) * KD + kg * 8;
  float acc[4][8];
  #pragma unroll
  for (int i = 0; i < 4; ++i)
    #pragma unroll
    for (int j = 0; j < 8; ++j) acc[i][j] = 0.f;
  #pragma unroll 8
  for (int d = 0; d < 256; ++d) {   // unroll 8: keep ~16 W loads in flight
    float4 w0 = *(const float4*)(wp + (size_t)d * KD);
    float4 w1 = *(const float4*)(wp + (size_t)d * KD + 4);
    float xv[4];
    #pragma unroll
    for (int i = 0; i < 4; ++i) xv[i] = xs[b0 + i][d];
    #pragma unroll
    for (int i = 0; i < 4; ++i) {
      acc[i][0] += xv[i] * w0.x; acc[i][1] += xv[i] * w0.y;
      acc[i][2] += xv[i] * w0.z; acc[i][3] += xv[i] * w0.w;
      acc[i][4] += xv[i] * w1.x; acc[i][5] += xv[i] * w1.y;
      acc[i][6] += xv[i] * w1.z; acc[i][7] += xv[i] * w1.w;
    }
  }
  #pragma unroll
  for (int i = 0; i < 4; ++i) {
    size_t base = ((size_t)(dc * 64 + b0 + i) * 34 + hx) * KD + kg * 8;
    *(float4*)&P[base]     = make_float4(acc[i][0], acc[i][1], acc[i][2], acc[i][3]);
    *(float4*)&P[base + 4] = make_float4(acc[i][4], acc[i][5], acc[i][6], acc[i][7]);
  }
}

// ---------------- K1b: reduce partials -> q, Kc[.,M,:], Vc[.,M,:] ----------
__global__ __launch_bounds__(256) void k_proj_reduce(
    const float* __restrict__ P, float* __restrict__ q,
    float* __restrict__ Kc, float* __restrict__ Vc) {
  int i = blockIdx.x * 256 + threadIdx.x;  // < 64*34*128 = 278528
  int k = i & 127;
  int hx = (i >> 7) % 34;
  int b = i / (128 * 34);
  float s = 0.f;
  #pragma unroll
  for (int dc = 0; dc < 16; ++dc)
    s += P[(size_t)dc * (64 * 34 * 128) + (size_t)(b * 34 + hx) * 128 + k];
  if (hx < H_)       q[((size_t)b * H_ + hx) * KD + k] = s;
  else if (hx == H_) Kc[((size_t)b * M1_ + M_) * KD + k] = s;
  else               Vc[((size_t)b * M1_ + M_) * VD + k] = s;
}

// ---------------- K2: flash attention chunk kernel -------------------------
// grid (32 m-chunks of 128, 64 b). Streams K then V in 32-row quarters
// through one small LDS buffer (52 KB total -> 3 blocks/CU so staging of one
// block overlaps compute of the other two). Inline load->LDS->Kc/Vc staging.
__global__ __launch_bounds__(256, 3) void k_flash(
    const float* __restrict__ prevK, const float* __restrict__ prevV,
    const float* __restrict__ q, float* __restrict__ Kc, float* __restrict__ Vc,
    float* __restrict__ o_part, float* __restrict__ stats) {
  __shared__ float buf[32][132];   // 16.9 KB quarter staging
  __shared__ float qs[32][132];    // 16.9 KB
  __shared__ float wl[128][36];    // 18.4 KB logits/weights [m][h]
  const int chunk = blockIdx.x;    // 0..31
  const int b = blockIdx.y;
  const int t = threadIdx.x;
  const int m0 = chunk * 128;

  // stage q tile [32][128]
  const float* qsrc = q + (size_t)b * H_ * KD;
  #pragma unroll
  for (int j = 0; j < 4; ++j) {
    int f = t + 256 * j, row = f >> 5, c4 = f & 31;
    *(float4*)&qs[row][c4 * 4] =
        *(const float4*)(qsrc + (size_t)row * KD + c4 * 4);
  }

  // ---- Phase 1: K quarters -> logits in wl ----
  const int hg = t >> 4, mg = t & 15, h0 = hg * 2;
  for (int qt = 0; qt < 4; ++qt) {
    __syncthreads();   // buf free (and qs ready on first iter)
    #pragma unroll
    for (int j = 0; j < 4; ++j) {
      int f = t + 256 * j, r = f >> 5, c4 = f & 31;
      int m = m0 + qt * 32 + r;
      float4 v;
      if (m < M_) v = *(const float4*)(prevK + ((size_t)b * M_ + m) * KD + c4 * 4);
      else        v = *(const float4*)(Kc + ((size_t)b * M1_ + M_) * KD + c4 * 4);
      *(float4*)&buf[r][c4 * 4] = v;
      if (m < M_) *(float4*)(Kc + ((size_t)b * M1_ + m) * KD + c4 * 4) = v;
    }
    __syncthreads();
    float acc00 = 0.f, acc01 = 0.f, acc10 = 0.f, acc11 = 0.f;
    #pragma unroll 4
    for (int k4 = 0; k4 < 32; ++k4) {
      float4 qa = *(const float4*)&qs[h0][k4 * 4];
      float4 qb = *(const float4*)&qs[h0 + 1][k4 * 4];
      float4 k0 = *(const float4*)&buf[mg][k4 * 4];
      float4 k1 = *(const float4*)&buf[mg + 16][k4 * 4];
      acc00 += qa.x * k0.x + qa.y * k0.y + qa.z * k0.z + qa.w * k0.w;
      acc01 += qa.x * k1.x + qa.y * k1.y + qa.z * k1.z + qa.w * k1.w;
      acc10 += qb.x * k0.x + qb.y * k0.y + qb.z * k0.z + qb.w * k0.w;
      acc11 += qb.x * k1.x + qb.y * k1.y + qb.z * k1.z + qb.w * k1.w;
    }
    wl[qt * 32 + mg][h0]          = acc00;
    wl[qt * 32 + mg + 16][h0]     = acc01;
    wl[qt * 32 + mg][h0 + 1]      = acc10;
    wl[qt * 32 + mg + 16][h0 + 1] = acc11;
  }
  __syncthreads();                 // wl fully written

  // ---- Phase 2: chunk-local softmax over wl columns ----
  {
    const int h = t >> 3, s8 = t & 7;   // 8 threads per h
    float vals[16];
    float mx = -3.402823466e38f;
    #pragma unroll
    for (int i = 0; i < 16; ++i) {      // m = i*8 + s8 (strided: avoids bank alias)
      vals[i] = wl[i * 8 + s8][h];
      mx = fmaxf(mx, vals[i]);
    }
    mx = fmaxf(mx, __shfl_xor(mx, 1));
    mx = fmaxf(mx, __shfl_xor(mx, 2));
    mx = fmaxf(mx, __shfl_xor(mx, 4));
    float sum = 0.f;
    #pragma unroll
    for (int i = 0; i < 16; ++i) {
      float e = exp2f((vals[i] - mx) * LOG2E);
      wl[i * 8 + s8][h] = e;
      sum += e;
    }
    sum += __shfl_xor(sum, 1);
    sum += __shfl_xor(sum, 2);
    sum += __shfl_xor(sum, 4);
    if (s8 == 0) {
      size_t sb = (((size_t)b * H_ + h) * NCHUNK + chunk) * 2;
      stats[sb]     = mx;
      stats[sb + 1] = sum;
    }
  }

  // ---- Phase 3: V quarters -> partial o ----
  const int hg2 = t >> 5, vg = t & 31;
  const int h0v = hg2 * 4, v0 = vg * 4;
  float acc2[4][4];
  #pragma unroll
  for (int hi = 0; hi < 4; ++hi)
    #pragma unroll
    for (int vi = 0; vi < 4; ++vi) acc2[hi][vi] = 0.f;
  for (int qt = 0; qt < 4; ++qt) {
    __syncthreads();   // softmax done (qt=0) / previous PV done
    #pragma unroll
    for (int j = 0; j < 4; ++j) {
      int f = t + 256 * j, r = f >> 5, c4 = f & 31;
      int m = m0 + qt * 32 + r;
      float4 v;
      if (m < M_) v = *(const float4*)(prevV + ((size_t)b * M_ + m) * VD + c4 * 4);
      else        v = *(const float4*)(Vc + ((size_t)b * M1_ + M_) * VD + c4 * 4);
      *(float4*)&buf[r][c4 * 4] = v;
      if (m < M_) *(float4*)(Vc + ((size_t)b * M1_ + m) * VD + c4 * 4) = v;
    }
    __syncthreads();
    #pragma unroll 4
    for (int mm = 0; mm < 32; ++mm) {
      float4 w4 = *(const float4*)&wl[qt * 32 + mm][h0v];
      float4 v4 = *(const float4*)&buf[mm][v0];
      float wv[4] = {w4.x, w4.y, w4.z, w4.w};
      float vv[4] = {v4.x, v4.y, v4.z, v4.w};
      #pragma unroll
      for (int hi = 0; hi < 4; ++hi)
        #pragma unroll
        for (int vi = 0; vi < 4; ++vi) acc2[hi][vi] += wv[hi] * vv[vi];
    }
  }
  #pragma unroll
  for (int hi = 0; hi < 4; ++hi) {
    size_t base = ((size_t)(chunk * B_ + b) * H_ + h0v + hi) * VD + v0;
    *(float4*)&o_part[base] =
        make_float4(acc2[hi][0], acc2[hi][1], acc2[hi][2], acc2[hi][3]);
  }
}

// ---------------- K3: flash combine -> o -----------------------------------
// grid 2048 = (b*H + h); 128 threads (one per v)
__global__ __launch_bounds__(128) void k_combine(
    const float* __restrict__ o_part, const float* __restrict__ stats,
    float* __restrict__ o) {
  const int bh = blockIdx.x;
  const int t = threadIdx.x;
  __shared__ float st[64];
  if (t < 64) st[t] = stats[(size_t)bh * 64 + t];
  __syncthreads();
  float M = -3.402823466e38f;
  #pragma unroll
  for (int c = 0; c < NCHUNK; ++c) M = fmaxf(M, st[2 * c]);
  float wc[NCHUNK];
  float denom = 0.f;
  #pragma unroll
  for (int c = 0; c < NCHUNK; ++c) {
    float e = exp2f((st[2 * c] - M) * LOG2E);
    wc[c] = e;
    denom += st[2 * c + 1] * e;
  }
  const float inv = 1.0f / denom;
  const int b = bh >> 5, h = bh & 31;
  float acc = 0.f;
  #pragma unroll 4
  for (int c = 0; c < NCHUNK; ++c)
    acc += wc[c] * o_part[((size_t)(c * B_ + b) * H_ + h) * VD + t];
  o[(size_t)bh * VD + t] = acc * inv;
}

// ---------------- K5: partial y = o . Wo -----------------------------------
// grid (32 d-chunks of 128, 16 hv-chunks of 256)
__global__ __launch_bounds__(256) void k_out_partial(
    const float* __restrict__ o, const float* __restrict__ Wo,
    float* __restrict__ Py) {
  __shared__ float os[64][256];   // 64 KB -> 2 blocks/CU
  const int dc = blockIdx.x;      // 0..31
  const int hvc = blockIdx.y;     // 0..15
  const int t = threadIdx.x;
  #pragma unroll
  for (int j = 0; j < 16; ++j) {
    int f = t + 256 * j;          // 0..4095 f4 over [64][64]
    int row = f >> 6, c4 = f & 63;
    *(float4*)&os[row][c4 * 4] =
        *(const float4*)(o + (size_t)row * 4096 + hvc * 256 + c4 * 4);
  }
  __syncthreads();
  const int bq = t >> 4, dg = t & 15;
  const int b0 = bq * 4;
  const float* wp = Wo + (size_t)(hvc * 256) * D_ + dc * 128 + dg * 8;
  float acc[4][8];
  #pragma unroll
  for (int i = 0; i < 4; ++i)
    #pragma unroll
    for (int j = 0; j < 8; ++j) acc[i][j] = 0.f;
  #pragma unroll 8
  for (int hv = 0; hv < 256; ++hv) {  // unroll 8: keep ~16 Wo loads in flight
    float4 w0 = *(const float4*)(wp + (size_t)hv * D_);
    float4 w1 = *(const float4*)(wp + (size_t)hv * D_ + 4);
    float ov[4];
    #pragma unroll
    for (int i = 0; i < 4; ++i) ov[i] = os[b0 + i][hv];
    #pragma unroll
    for (int i = 0; i < 4; ++i) {
      acc[i][0] += ov[i] * w0.x; acc[i][1] += ov[i] * w0.y;
      acc[i][2] += ov[i] * w0.z; acc[i][3] += ov[i] * w0.w;
      acc[i][4] += ov[i] * w1.x; acc[i][5] += ov[i] * w1.y;
      acc[i][6] += ov[i] * w1.z; acc[i][7] += ov[i] * w1.w;
    }
  }
  #pragma unroll
  for (int i = 0; i < 4; ++i) {
    size_t base = ((size_t)hvc * 64 + b0 + i) * 4096 + dc * 128 + dg * 8;
    *(float4*)&Py[base]     = make_float4(acc[i][0], acc[i][1], acc[i][2], acc[i][3]);
    *(float4*)&Py[base + 4] = make_float4(acc[i][4], acc[i][5], acc[i][6], acc[i][7]);
  }
}

// ---------------- K5b: reduce partial y ------------------------------------
__global__ __launch_bounds__(256) void k_yreduce(
    const float* __restrict__ Py, float* __restrict__ y) {
  int i = blockIdx.x * 256 + threadIdx.x;  // < 262144
  float s = 0.f;
  #pragma unroll
  for (int c = 0; c < 16; ++c) s += Py[(size_t)c * 262144 + i];
  y[i] = s;
}

extern "C" void kernel_launch(void* const* d_in, const int* in_sizes, int n_in,
                              void* d_out, int out_size, void* d_ws, size_t ws_size,
                              hipStream_t stream) {
  const float* x     = (const float*)d_in[0];
  const float* prevK = (const float*)d_in[1];
  const float* prevV = (const float*)d_in[2];
  const float* Wq    = (const float*)d_in[3];
  const float* Wk    = (const float*)d_in[4];
  const float* Wv    = (const float*)d_in[5];
  const float* Wo    = (const float*)d_in[6];

  float* y  = (float*)d_out;                 // [64][4096]
  float* Kc = y + (size_t)B_ * D_;           // [64][4096][128]
  float* Vc = Kc + (size_t)B_ * M1_ * KD;    // [64][4096][128]

  float* ws     = (float*)d_ws;
  float* P      = ws + WS_P;       // proj partials, later Py
  float* q      = ws + WS_Q;
  float* stats  = ws + WS_STATS;
  float* o      = ws + WS_O;
  float* o_part = ws + WS_OPART;

  k_proj_partial<<<dim3(16, 34), 256, 0, stream>>>(x, Wq, Wk, Wv, P);
  k_proj_reduce<<<1088, 256, 0, stream>>>(P, q, Kc, Vc);
  k_flash<<<dim3(32, 64), 256, 0, stream>>>(prevK, prevV, q, Kc, Vc, o_part, stats);
  k_combine<<<2048, 128, 0, stream>>>(o_part, stats, o);
  k_out_partial<<<dim3(32, 16), 256, 0, stream>>>(o, Wo, P);
  k_yreduce<<<1024, 256, 0, stream>>>(P, y);
}